// Round 1
// baseline (327.881 us; speedup 1.0000x reference)
//
#include <hip/hip_runtime.h>

typedef unsigned short ushort_t;
typedef __bf16 bf16x8 __attribute__((ext_vector_type(8)));
typedef float f32x4 __attribute__((ext_vector_type(4)));

__device__ __forceinline__ unsigned short f2bf(float f) {
    unsigned u = __float_as_uint(f);
    u += 0x7fffu + ((u >> 16) & 1u);
    return (unsigned short)(u >> 16);
}
__device__ __forceinline__ float bf2f(unsigned short h) {
    return __uint_as_float(((unsigned)h) << 16);
}
__device__ __forceinline__ float gelu_f(float x) {
    return 0.5f * x * (1.0f + erff(x * 0.70710678118654752440f));
}

// ---------------- convert X = [former | hidden] -> bf16 [16384][2048] ----------------
__global__ void convert_x_kernel(const float4* __restrict__ former,
                                 const float4* __restrict__ hidden,
                                 ushort4* __restrict__ Xb)
{
    int i = blockIdx.x * 256 + threadIdx.x;   // < 16384*512
    int row = i >> 9;
    int g = i & 511;
    float4 v = (g < 256) ? former[row * 256 + g] : hidden[row * 256 + (g - 256)];
    Xb[i] = make_ushort4(f2bf(v.x), f2bf(v.y), f2bf(v.z), f2bf(v.w));
}

// ---------------- tiled transpose f32 [R][C] -> bf16 [C][R] ----------------
__global__ void transpose_bf_kernel(const float* __restrict__ W, ushort_t* __restrict__ Wt,
                                    int R, int C)
{
    __shared__ float tile[32][33];
    const int bx = blockIdx.x * 32;  // C dim
    const int by = blockIdx.y * 32;  // R dim
    const int tx = threadIdx.x, ty = threadIdx.y;
    #pragma unroll
    for (int j = 0; j < 32; j += 8)
        tile[ty + j][tx] = W[(size_t)(by + ty + j) * C + bx + tx];
    __syncthreads();
    #pragma unroll
    for (int j = 0; j < 32; j += 8)
        Wt[(size_t)(bx + ty + j) * R + by + tx] = f2bf(tile[tx][ty + j]);
}

// ---------------- m97-style bf16 GEMM: C = gelu(A @ Bt^T + bias) ----------------
// A: [M][K] bf16 row-major, Bt: [N][K] bf16 row-major, C: [M][N] (bf16 or f32)
template <bool OUT_BF16>
__global__ void gemm_bias_gelu_kernel(const ushort_t* __restrict__ A,
                                      const ushort_t* __restrict__ Bt,
                                      const float* __restrict__ bias,
                                      void* __restrict__ C,
                                      int M, int N, int K)
{
    __shared__ __align__(16) ushort_t sA[128 * 64];
    __shared__ __align__(16) ushort_t sB[128 * 64];
    const int tid  = threadIdx.x;
    const int lane = tid & 63;
    const int wave = tid >> 6;
    const int wm = (wave & 1) * 64;
    const int wn = (wave >> 1) * 64;
    const long bm = (long)blockIdx.x * 128;
    const long bn = (long)blockIdx.y * 128;

    f32x4 acc[4][4] = {};

    // staging: chunk c = it*256 + wave*64 + lane, 16B each
    const int srow = wave * 8 + (lane >> 3);   // + it*32
    const int scol = (lane & 7) * 8;
    const int ldsbase = wave * 512;            // ushort index; + it*2048

    for (int k0 = 0; k0 < K; k0 += 64) {
        __syncthreads();
        #pragma unroll
        for (int it = 0; it < 4; ++it) {
            const ushort_t* gA = A + (size_t)(bm + it * 32 + srow) * K + k0 + scol;
            const ushort_t* gB = Bt + (size_t)(bn + it * 32 + srow) * K + k0 + scol;
            __builtin_amdgcn_global_load_lds(
                (__attribute__((address_space(1))) void*)gA,
                (__attribute__((address_space(3))) void*)&sA[ldsbase + it * 2048], 16, 0, 0);
            __builtin_amdgcn_global_load_lds(
                (__attribute__((address_space(1))) void*)gB,
                (__attribute__((address_space(3))) void*)&sB[ldsbase + it * 2048], 16, 0, 0);
        }
        __syncthreads();

        const int arow = wm + (lane & 15);
        const int brow = wn + (lane & 15);
        const int kb = (lane >> 4) * 8;
        #pragma unroll
        for (int kk = 0; kk < 64; kk += 32) {
            bf16x8 af[4], bfr[4];
            #pragma unroll
            for (int t = 0; t < 4; ++t) {
                af[t]  = *(const bf16x8*)&sA[(arow + t * 16) * 64 + kk + kb];
                bfr[t] = *(const bf16x8*)&sB[(brow + t * 16) * 64 + kk + kb];
            }
            #pragma unroll
            for (int i = 0; i < 4; ++i)
                #pragma unroll
                for (int j = 0; j < 4; ++j)
                    acc[i][j] = __builtin_amdgcn_mfma_f32_16x16x32_bf16(af[i], bfr[j], acc[i][j], 0, 0, 0);
        }
    }

    // epilogue: C/D layout col=lane&15, row=(lane>>4)*4+reg   [m89/m91 verified]
    #pragma unroll
    for (int i = 0; i < 4; ++i) {
        const long row0 = bm + wm + i * 16 + (lane >> 4) * 4;
        #pragma unroll
        for (int j = 0; j < 4; ++j) {
            const long col = bn + wn + j * 16 + (lane & 15);
            const float bv = bias[col];
            #pragma unroll
            for (int r = 0; r < 4; ++r) {
                float v = gelu_f(acc[i][j][r] + bv);
                if (OUT_BF16)
                    ((ushort_t*)C)[(size_t)(row0 + r) * N + col] = f2bf(v);
                else
                    ((float*)C)[(size_t)(row0 + r) * N + col] = v;
            }
        }
    }
}

// ---------------- segment sum: cell[b,t,:] = sum_{l: ids[b,l]==t} seq[b,l,:] ----------------
__global__ void segsum_kernel(const ushort_t* __restrict__ seq,   // [8*2048][1024] bf16
                              const int* __restrict__ ids,        // [8][2048]
                              ushort_t* __restrict__ cell)        // [8*256][1024] bf16
{
    const int b = blockIdx.x >> 8;
    const int t = blockIdx.x & 255;
    __shared__ int list[2048];
    __shared__ int count;
    if (threadIdx.x == 0) count = 0;
    __syncthreads();
    const int* idrow = ids + b * 2048;
    for (int l = threadIdx.x; l < 2048; l += 256) {
        if (idrow[l] == t) list[atomicAdd(&count, 1)] = l;
    }
    __syncthreads();
    const int n = count;
    float a0 = 0.f, a1 = 0.f, a2 = 0.f, a3 = 0.f;
    for (int i = 0; i < n; ++i) {
        const int l = list[i];
        const ushort4 v = *(const ushort4*)(seq + (size_t)(b * 2048 + l) * 1024 + threadIdx.x * 4);
        a0 += bf2f(v.x); a1 += bf2f(v.y); a2 += bf2f(v.z); a3 += bf2f(v.w);
    }
    ushort4* out = (ushort4*)(cell + (size_t)(b * 256 + t) * 1024);
    out[threadIdx.x] = make_ushort4(f2bf(a0), f2bf(a1), f2bf(a2), f2bf(a3));
}

// ---------------- gather: out[b,l,:] = cellout[b, ids[b,l], :] ----------------
__global__ void gather_kernel(const float4* __restrict__ cellout,  // [8*256][256] float4
                              const int* __restrict__ ids,
                              float4* __restrict__ out)            // [8*2048][256] float4
{
    const int tok = blockIdx.x;           // b*2048 + l
    const int b = tok >> 11;
    const int t = ids[tok];
    out[(size_t)tok * 256 + threadIdx.x] = cellout[(size_t)(b * 256 + t) * 256 + threadIdx.x];
}

extern "C" void kernel_launch(void* const* d_in, const int* in_sizes, int n_in,
                              void* d_out, int out_size, void* d_ws, size_t ws_size,
                              hipStream_t stream) {
    const float* former = (const float*)d_in[0];   // [8,2048,1024] f32
    const float* hidden = (const float*)d_in[1];   // [8,2048,1024] f32
    const int*   ids    = (const int*)d_in[2];     // [8,2048] i32
    // d_in[3] attention_mask: unused by reference
    const float* W_down = (const float*)d_in[4];   // [2048,1024] f32
    const float* b_down = (const float*)d_in[5];   // [1024] f32
    const float* W_row  = (const float*)d_in[6];   // [1024,1024] f32
    const float* b_row  = (const float*)d_in[7];   // [1024] f32
    float* out = (float*)d_out;                    // [8,2048,1024] f32

    char* ws = (char*)d_ws;
    ushort_t* Xb    = (ushort_t*)ws;  ws += (size_t)16384 * 2048 * 2;  // 64 MiB
    ushort_t* WdT   = (ushort_t*)ws;  ws += (size_t)1024 * 2048 * 2;   //  4 MiB
    ushort_t* WrT   = (ushort_t*)ws;  ws += (size_t)1024 * 1024 * 2;   //  2 MiB
    ushort_t* seq   = (ushort_t*)ws;  ws += (size_t)16384 * 1024 * 2;  // 32 MiB
    ushort_t* cellb = (ushort_t*)ws;  ws += (size_t)2048 * 1024 * 2;   //  4 MiB
    float*    cello = (float*)ws;                                      //  8 MiB

    convert_x_kernel<<<32768, 256, 0, stream>>>((const float4*)former, (const float4*)hidden,
                                                (ushort4*)Xb);
    transpose_bf_kernel<<<dim3(32, 64), dim3(32, 8), 0, stream>>>(W_down, WdT, 2048, 1024);
    transpose_bf_kernel<<<dim3(32, 32), dim3(32, 8), 0, stream>>>(W_row, WrT, 1024, 1024);

    // GEMM1: [16384 x 2048] @ [2048 x 1024] -> gelu -> bf16 seq
    gemm_bias_gelu_kernel<true><<<dim3(128, 8), 256, 0, stream>>>(Xb, WdT, b_down, seq,
                                                                  16384, 1024, 2048);
    segsum_kernel<<<2048, 256, 0, stream>>>(seq, ids, cellb);

    // GEMM2: [2048 x 1024] @ [1024 x 1024] -> gelu -> f32 cello
    gemm_bias_gelu_kernel<false><<<dim3(16, 8), 256, 0, stream>>>(cellb, WrT, b_row, cello,
                                                                  2048, 1024, 1024);
    gather_kernel<<<16384, 256, 0, stream>>>((const float4*)cello, ids, (float4*)out);
}

// Round 2
// 318.104 us; speedup vs baseline: 1.0307x; 1.0307x over previous
//
#include <hip/hip_runtime.h>

typedef unsigned short ushort_t;
typedef __bf16 bf16x8 __attribute__((ext_vector_type(8)));
typedef float f32x4 __attribute__((ext_vector_type(4)));

__device__ __forceinline__ unsigned short f2bf(float f) {
    unsigned u = __float_as_uint(f);
    u += 0x7fffu + ((u >> 16) & 1u);
    return (unsigned short)(u >> 16);
}
__device__ __forceinline__ float bf2f(unsigned short h) {
    return __uint_as_float(((unsigned)h) << 16);
}
__device__ __forceinline__ float gelu_f(float x) {
    return 0.5f * x * (1.0f + erff(x * 0.70710678118654752440f));
}

// ---------------- prep: convert X -> bf16 AND transpose both weights ----------------
// blocks [0,16384): X rows; [16384,18432): W_down transpose; [18432,19456): W_row transpose
__global__ void prep_kernel(const float4* __restrict__ former,
                            const float4* __restrict__ hidden,
                            uint4* __restrict__ Xb4,
                            const float* __restrict__ Wd, ushort_t* __restrict__ WdT,
                            const float* __restrict__ Wr, ushort_t* __restrict__ WrT)
{
    const int blk = blockIdx.x;
    const int tid = threadIdx.x;
    if (blk < 16384) {
        // one X row per block: cols 0-1023 from former, 1024-2047 from hidden
        const int row = blk;
        const float4* src = (tid < 128)
            ? (former + (size_t)row * 256 + (tid & 127) * 2)
            : (hidden + (size_t)row * 256 + (tid & 127) * 2);
        float4 a = src[0], b = src[1];
        uint4 o;
        o.x = f2bf(a.x) | ((unsigned)f2bf(a.y) << 16);
        o.y = f2bf(a.z) | ((unsigned)f2bf(a.w) << 16);
        o.z = f2bf(b.x) | ((unsigned)f2bf(b.y) << 16);
        o.w = f2bf(b.z) | ((unsigned)f2bf(b.w) << 16);
        Xb4[(size_t)row * 256 + tid] = o;
    } else {
        // tiled transpose f32 [R][C] -> bf16 [C][R]
        __shared__ float tile[32][33];
        const float* W; ushort_t* Wt; int R, C, b;
        if (blk < 16384 + 2048) { b = blk - 16384; W = Wd; Wt = WdT; R = 2048; C = 1024; }
        else                    { b = blk - 18432; W = Wr; Wt = WrT; R = 1024; C = 1024; }
        const int bx = (b & 31) * 32;
        const int by = (b >> 5) * 32;
        const int tx = tid & 31, ty = tid >> 5;
        #pragma unroll
        for (int j = 0; j < 32; j += 8)
            tile[ty + j][tx] = W[(size_t)(by + ty + j) * C + bx + tx];
        __syncthreads();
        #pragma unroll
        for (int j = 0; j < 32; j += 8)
            Wt[(size_t)(bx + ty + j) * R + by + tx] = f2bf(tile[tx][ty + j]);
    }
}

// ---------------- m97-style bf16 GEMM with XOR-swizzled LDS: C = gelu(A @ Bt^T + bias) ----
// A: [M][K] bf16 row-major, Bt: [N][K] bf16 row-major, C: [M][N] (bf16 or f32)
// LDS chunk cl (16B) of row r holds global chunk cl ^ (r&7): kills the 16-way
// bank conflict of the stride-128B row layout while keeping global_load_lds's
// wave-uniform-base placement and full global coalescing.
template <bool OUT_BF16>
__global__ void gemm_bias_gelu_kernel(const ushort_t* __restrict__ A,
                                      const ushort_t* __restrict__ Bt,
                                      const float* __restrict__ bias,
                                      void* __restrict__ C,
                                      int M, int N, int K)
{
    __shared__ __align__(16) ushort_t sA[128 * 64];
    __shared__ __align__(16) ushort_t sB[128 * 64];
    const int tid  = threadIdx.x;
    const int lane = tid & 63;
    const int wave = tid >> 6;
    const int wm = (wave & 1) * 64;
    const int wn = (wave >> 1) * 64;
    const long bm = (long)blockIdx.x * 128;
    const long bn = (long)blockIdx.y * 128;

    f32x4 acc[4][4] = {};

    // staging: lane l of wave w (+ section it) covers row = it*32 + w*8 + (l>>3).
    // row&7 == l>>3, so the swizzled global chunk is (l&7) ^ (l>>3).
    const int srow = wave * 8 + (lane >> 3);
    const int scol = ((lane & 7) ^ (lane >> 3)) * 8;
    const int ldsbase = wave * 512;

    for (int k0 = 0; k0 < K; k0 += 64) {
        __syncthreads();
        #pragma unroll
        for (int it = 0; it < 4; ++it) {
            const ushort_t* gA = A + (size_t)(bm + it * 32 + srow) * K + k0 + scol;
            const ushort_t* gB = Bt + (size_t)(bn + it * 32 + srow) * K + k0 + scol;
            __builtin_amdgcn_global_load_lds(
                (__attribute__((address_space(1))) void*)gA,
                (__attribute__((address_space(3))) void*)&sA[ldsbase + it * 2048], 16, 0, 0);
            __builtin_amdgcn_global_load_lds(
                (__attribute__((address_space(1))) void*)gB,
                (__attribute__((address_space(3))) void*)&sB[ldsbase + it * 2048], 16, 0, 0);
        }
        __syncthreads();

        // fragment rows: arow&7 == lane&7 (wm,wn,t*16 are ≡0 mod 8) → lane-constant sw
        const int arow = wm + (lane & 15);
        const int brow = wn + (lane & 15);
        const int sw = lane & 7;
        const int cbase = lane >> 4;
        #pragma unroll
        for (int kk = 0; kk < 64; kk += 32) {
            const int koff = (((kk >> 3) + cbase) ^ sw) << 3;
            bf16x8 af[4], bfr[4];
            #pragma unroll
            for (int t = 0; t < 4; ++t) {
                af[t]  = *(const bf16x8*)&sA[(arow + t * 16) * 64 + koff];
                bfr[t] = *(const bf16x8*)&sB[(brow + t * 16) * 64 + koff];
            }
            #pragma unroll
            for (int i = 0; i < 4; ++i)
                #pragma unroll
                for (int j = 0; j < 4; ++j)
                    acc[i][j] = __builtin_amdgcn_mfma_f32_16x16x32_bf16(af[i], bfr[j], acc[i][j], 0, 0, 0);
        }
    }

    // epilogue: C/D layout col=lane&15, row=(lane>>4)*4+reg   [m89/m91 verified]
    #pragma unroll
    for (int i = 0; i < 4; ++i) {
        const long row0 = bm + wm + i * 16 + (lane >> 4) * 4;
        #pragma unroll
        for (int j = 0; j < 4; ++j) {
            const long col = bn + wn + j * 16 + (lane & 15);
            const float bv = bias[col];
            #pragma unroll
            for (int r = 0; r < 4; ++r) {
                float v = gelu_f(acc[i][j][r] + bv);
                if (OUT_BF16)
                    ((ushort_t*)C)[(size_t)(row0 + r) * N + col] = f2bf(v);
                else
                    ((float*)C)[(size_t)(row0 + r) * N + col] = v;
            }
        }
    }
}

// ---------------- segment sum: cell[b,t,:] = sum_{l: ids[b,l]==t} seq[b,l,:] ----------------
__global__ void segsum_kernel(const ushort_t* __restrict__ seq,   // [8*2048][1024] bf16
                              const int* __restrict__ ids,        // [8][2048]
                              ushort_t* __restrict__ cell)        // [8*256][1024] bf16
{
    const int b = blockIdx.x >> 8;
    const int t = blockIdx.x & 255;
    __shared__ int list[2048];
    __shared__ int count;
    if (threadIdx.x == 0) count = 0;
    __syncthreads();
    const int* idrow = ids + b * 2048;
    for (int l = threadIdx.x; l < 2048; l += 256) {
        if (idrow[l] == t) list[atomicAdd(&count, 1)] = l;
    }
    __syncthreads();
    const int n = count;
    float a0 = 0.f, a1 = 0.f, a2 = 0.f, a3 = 0.f;
    for (int i = 0; i < n; ++i) {
        const int l = list[i];
        const ushort4 v = *(const ushort4*)(seq + (size_t)(b * 2048 + l) * 1024 + threadIdx.x * 4);
        a0 += bf2f(v.x); a1 += bf2f(v.y); a2 += bf2f(v.z); a3 += bf2f(v.w);
    }
    ushort4* out = (ushort4*)(cell + (size_t)(b * 256 + t) * 1024);
    out[threadIdx.x] = make_ushort4(f2bf(a0), f2bf(a1), f2bf(a2), f2bf(a3));
}

// ---------------- gather: out[b,l,:] = cellout[b, ids[b,l], :] ----------------
__global__ void gather_kernel(const float4* __restrict__ cellout,  // [8*256][256] float4
                              const int* __restrict__ ids,
                              float4* __restrict__ out)            // [8*2048][256] float4
{
    const int tok = blockIdx.x;           // b*2048 + l
    const int b = tok >> 11;
    const int t = ids[tok];
    out[(size_t)tok * 256 + threadIdx.x] = cellout[(size_t)(b * 256 + t) * 256 + threadIdx.x];
}

extern "C" void kernel_launch(void* const* d_in, const int* in_sizes, int n_in,
                              void* d_out, int out_size, void* d_ws, size_t ws_size,
                              hipStream_t stream) {
    const float* former = (const float*)d_in[0];   // [8,2048,1024] f32
    const float* hidden = (const float*)d_in[1];   // [8,2048,1024] f32
    const int*   ids    = (const int*)d_in[2];     // [8,2048] i32
    // d_in[3] attention_mask: unused by reference
    const float* W_down = (const float*)d_in[4];   // [2048,1024] f32
    const float* b_down = (const float*)d_in[5];   // [1024] f32
    const float* W_row  = (const float*)d_in[6];   // [1024,1024] f32
    const float* b_row  = (const float*)d_in[7];   // [1024] f32
    float* out = (float*)d_out;                    // [8,2048,1024] f32

    char* ws = (char*)d_ws;
    ushort_t* Xb    = (ushort_t*)ws;  ws += (size_t)16384 * 2048 * 2;  // 64 MiB
    ushort_t* WdT   = (ushort_t*)ws;  ws += (size_t)1024 * 2048 * 2;   //  4 MiB
    ushort_t* WrT   = (ushort_t*)ws;  ws += (size_t)1024 * 1024 * 2;   //  2 MiB
    ushort_t* seq   = (ushort_t*)ws;  ws += (size_t)16384 * 1024 * 2;  // 32 MiB
    ushort_t* cellb = (ushort_t*)ws;  ws += (size_t)2048 * 1024 * 2;   //  4 MiB
    float*    cello = (float*)ws;                                      //  8 MiB

    prep_kernel<<<19456, 256, 0, stream>>>((const float4*)former, (const float4*)hidden,
                                           (uint4*)Xb, W_down, WdT, W_row, WrT);

    // GEMM1: [16384 x 2048] @ [2048 x 1024] -> gelu -> bf16 seq
    gemm_bias_gelu_kernel<true><<<dim3(128, 8), 256, 0, stream>>>(Xb, WdT, b_down, seq,
                                                                  16384, 1024, 2048);
    segsum_kernel<<<2048, 256, 0, stream>>>(seq, ids, cellb);

    // GEMM2: [2048 x 1024] @ [1024 x 1024] -> gelu -> f32 cello
    gemm_bias_gelu_kernel<false><<<dim3(16, 8), 256, 0, stream>>>(cellb, WrT, b_row, cello,
                                                                  2048, 1024, 1024);
    gather_kernel<<<16384, 256, 0, stream>>>((const float4*)cello, ids, (float4*)out);
}